// Round 1
// baseline (96.822 us; speedup 1.0000x reference)
//
#include <hip/hip_runtime.h>
#include <hip/hip_bf16.h>

typedef __attribute__((ext_vector_type(8))) short short8;
typedef __attribute__((ext_vector_type(4))) float f32x4;

union U16x8 { uint4 u; short8 s; unsigned short us[8]; };

#define S_LEN 4096
#define DH    128
#define TQ    16          // queries per attn block
#define VTS   168         // V^T LDS row stride in u16 (21 groups of 8, 336B rows)
#define PST   168         // P LDS row stride in u16

// ---------------- Kernel 0: one-time prep ----------------------------------
// bid < 512 : x (fp32) -> XH/XL hi/lo bf16 split, contiguous (8 elems/thread)
// bid >= 512: W (fp32, row-major [k][col]) -> WT bf16 transposed [col][k]
//             via LDS tile so both global read and write are coalesced.
__global__ __launch_bounds__(256) void prep_kernel(
    const float* __restrict__ x,
    const float* __restrict__ Wq, const float* __restrict__ Wk,
    const float* __restrict__ Wv,
    unsigned short* __restrict__ XH, unsigned short* __restrict__ XL,
    unsigned short* __restrict__ WT)
{
    const int t = threadIdx.x;
    const int bid = blockIdx.x;

    __shared__ unsigned short T[128][136];   // padded: no bank conflict on col reads

    if (bid < 512) {
        size_t off = ((size_t)bid * 256 + t) * 8;
        float4 a = *(const float4*)(x + off);
        float4 b = *(const float4*)(x + off + 4);
        float xs[8] = {a.x, a.y, a.z, a.w, b.x, b.y, b.z, b.w};
        U16x8 h, l;
        #pragma unroll
        for (int j = 0; j < 8; ++j) {
            __hip_bfloat16 hb = __float2bfloat16(xs[j]);
            float hf = __bfloat162float(hb);
            __hip_bfloat16 lb = __float2bfloat16(xs[j] - hf);
            h.us[j] = *(unsigned short*)&hb;
            l.us[j] = *(unsigned short*)&lb;
        }
        *(uint4*)(XH + off) = h.u;
        *(uint4*)(XL + off) = l.u;
    } else {
        const int mat = bid - 512;
        const float* W = (mat == 0) ? Wq : (mat == 1) ? Wk : Wv;
        unsigned short* WTm = WT + mat * (128 * 128);
        #pragma unroll
        for (int c = 0; c < 8; ++c) {
            int linear = c * 2048 + t * 8;
            int kk = linear >> 7, col = linear & 127;
            float4 a = *(const float4*)(W + linear);
            float4 b = *(const float4*)(W + linear + 4);
            float ws[8] = {a.x, a.y, a.z, a.w, b.x, b.y, b.z, b.w};
            #pragma unroll
            for (int j = 0; j < 8; ++j) {
                __hip_bfloat16 wb = __float2bfloat16(ws[j]);
                T[kk][col + j] = *(unsigned short*)&wb;
            }
        }
        __syncthreads();
        #pragma unroll
        for (int c = 0; c < 8; ++c) {
            int linear = c * 2048 + t * 8;
            int col = linear >> 7, k0 = linear & 127;
            U16x8 u;
            #pragma unroll
            for (int j = 0; j < 8; ++j) u.us[j] = T[k0 + j][col];
            *(uint4*)(WTm + linear) = u.u;
        }
    }
}

// ---------------- Kernel 1: QKV projection via MFMA ------------------------
// All inputs pre-converted: A-frags are contiguous short8 from XH/XL, B-frags
// contiguous short8 from WT (L2-hot, 32 KB/mat). No LDS, no syncthreads,
// no cvt. Grid = (256 row-groups) x (3 mats) = 768 blocks = 3 blocks/CU.
__global__ __launch_bounds__(256) void qkv_kernel(
    const unsigned short* __restrict__ XH, const unsigned short* __restrict__ XL,
    const unsigned short* __restrict__ WT,
    const float* __restrict__ bq, const float* __restrict__ bk,
    const float* __restrict__ bv,
    __hip_bfloat16* __restrict__ q, __hip_bfloat16* __restrict__ k,
    __hip_bfloat16* __restrict__ v)
{
    const int t = threadIdx.x;
    const int wave = t >> 6, lane = t & 63;
    const int i = lane & 15, g = lane >> 4;
    const int row0 = blockIdx.x * 32;
    const int mat = blockIdx.y;

    const unsigned short* WTm = WT + mat * (128 * 128);
    const float* bias_p = (mat == 0) ? bq : (mat == 1) ? bk : bv;
    __hip_bfloat16* O = (mat == 0) ? q : (mat == 1) ? k : v;

    // A-frags: row m = rt*16+i, k = kc*32 + g*8 + j (contiguous)
    short8 ah[2][4], al[2][4];
    #pragma unroll
    for (int rt = 0; rt < 2; ++rt)
        #pragma unroll
        for (int kc = 0; kc < 4; ++kc) {
            size_t base = (size_t)(row0 + rt * 16 + i) * DH + kc * 32 + g * 8;
            ah[rt][kc] = *(const short8*)(XH + base);
            al[rt][kc] = *(const short8*)(XL + base);
        }

    #pragma unroll
    for (int ct = 0; ct < 2; ++ct) {
        const int col = wave * 32 + ct * 16 + i;
        const float bias = bias_p[col];

        short8 bf[4];
        #pragma unroll
        for (int kc = 0; kc < 4; ++kc)
            bf[kc] = *(const short8*)(WTm + col * DH + kc * 32 + g * 8);

        #pragma unroll
        for (int rt = 0; rt < 2; ++rt) {
            f32x4 acc; acc[0]=0.f; acc[1]=0.f; acc[2]=0.f; acc[3]=0.f;
            #pragma unroll
            for (int kc = 0; kc < 4; ++kc) {
                acc = __builtin_amdgcn_mfma_f32_16x16x32_bf16(ah[rt][kc], bf[kc], acc, 0, 0, 0);
                acc = __builtin_amdgcn_mfma_f32_16x16x32_bf16(al[rt][kc], bf[kc], acc, 0, 0, 0);
            }
            #pragma unroll
            for (int r = 0; r < 4; ++r) {
                O[(size_t)(row0 + rt * 16 + g * 4 + r) * DH + col] =
                    __float2bfloat16(acc[r] + bias);
            }
        }
    }
}

// ---- 8x8 u16 in-register transpose (32 v_perm) + swizzled VT write --------
__device__ inline void vt_xpose_write(unsigned short* VT, const uint4* vr,
                                      int kgp, int dgp)
{
    unsigned w[8][4];   // w[dim][key-pair]
    #pragma unroll
    for (int p = 0; p < 4; ++p) {
        #pragma unroll
        for (int j = 0; j < 4; ++j) {
            unsigned xlo = ((const unsigned*)&vr[2*p])[j];     // key 2p,  dims 2j,2j+1
            unsigned ylo = ((const unsigned*)&vr[2*p+1])[j];   // key 2p+1
            w[2*j][p]   = __builtin_amdgcn_perm(ylo, xlo, 0x05040100u);
            w[2*j+1][p] = __builtin_amdgcn_perm(ylo, xlo, 0x07060302u);
        }
    }
    int sw = kgp + (dgp & 7); if (sw >= 21) sw -= 21;   // bank swizzle, rotate mod 21
    #pragma unroll
    for (int d = 0; d < 8; ++d) {
        int row = dgp*8 + d;
        *(uint4*)&VT[row*VTS + sw*8] =
            make_uint4(w[d][0], w[d][1], w[d][2], w[d][3]);
    }
}

// ---------------- Kernel 2: MFMA sliding-window attention -------------------
// Block = 4 waves, 16 queries, 160-key staged window. Phase A: waves own key
// tiles {w, w+4, w+8}, B-frags gathered straight from global K (cached).
// V transposed into LDS via register 8x8 transpose. Phase B: waves own
// 32-dim strips, P & V^T frags are ds_read_b128.
// Block index is XCD-swizzled (512 % 8 == 0 -> bijective) so each XCD's
// resident q-tiles are contiguous -> K/V window stays L2-resident.
__global__ __launch_bounds__(256) void attn_kernel(
    const __hip_bfloat16* __restrict__ qg,
    const __hip_bfloat16* __restrict__ kg,
    const __hip_bfloat16* __restrict__ vg,
    float* __restrict__ out, const int* __restrict__ wsz)
{
    __shared__ __align__(16) unsigned short VT[128 * VTS];   // 43 KB
    __shared__ __align__(16) unsigned short Pm[TQ * PST];    // 5.25 KB
    __shared__ float pmax[4][16];
    __shared__ float psum[4][16];

    const int t    = threadIdx.x;
    const int wave = t >> 6, lane = t & 63;
    const int i = lane & 15, g = lane >> 4;
    const int bid  = blockIdx.x;
    const int qblk = (bid & 7) * 64 + (bid >> 3);   // XCD swizzle, 512 blocks
    const int b    = qblk >> 8;
    const int s0   = (qblk & 255) * TQ;
    const int k0   = s0 - 64;
    const int half = wsz[0] >> 1;
    const float scale = 0.08838834764831845f;

    const __hip_bfloat16* kb = kg + (size_t)b * S_LEN * DH;
    const __hip_bfloat16* vb = vg + (size_t)b * S_LEN * DH;

    // ---- V tile loads (issued first; 8 keys x 8 dims per tile) ----
    const int kgp0 = t >> 4, dgp0 = t & 15;          // tile t
    const bool two = (t & 3) == 0;
    const int tau2 = 256 + (t >> 2);                 // tiles 256..319
    const int kgp1 = tau2 >> 4, dgp1 = tau2 & 15;
    uint4 vr0[8], vr1[8];
    #pragma unroll
    for (int r = 0; r < 8; ++r) {
        int key = k0 + kgp0*8 + r;
        uint4 val = make_uint4(0u,0u,0u,0u);
        if (key >= 0 && key < S_LEN)
            val = *(const uint4*)(vb + (size_t)key * DH + dgp0*8);
        vr0[r] = val;
    }
    #pragma unroll
    for (int r = 0; r < 8; ++r) {
        int key = k0 + kgp1*8 + r;
        uint4 val = make_uint4(0u,0u,0u,0u);
        if (two && key >= 0 && key < S_LEN)
            val = *(const uint4*)(vb + (size_t)key * DH + dgp1*8);
        vr1[r] = val;
    }

    // ---- Q A-frags from global (same rows for all 4 waves -> L1 broadcast) ----
    short8 aq[4];
    {
        const __hip_bfloat16* qrow = qg + (size_t)(b * S_LEN + s0 + i) * DH;
        #pragma unroll
        for (int kc = 0; kc < 4; ++kc) {
            U16x8 u; u.u = *(const uint4*)(qrow + kc*32 + g*8);
            aq[kc] = u.s;
        }
    }

    // ---- Phase A: scores for owned key tiles, B-frags straight from global ----
    const int nkt = (wave < 2) ? 3 : 2;
    f32x4 acc[3];
    #pragma unroll
    for (int u = 0; u < 3; ++u) { acc[u][0]=0.f; acc[u][1]=0.f; acc[u][2]=0.f; acc[u][3]=0.f; }
    #pragma unroll
    for (int u = 0; u < 3; ++u) {
        if (u < nkt) {
            int kt = wave + 4*u;
            int key = k0 + kt*16 + i;               // may be OOB: garbage -> masked
            const __hip_bfloat16* krow = kb + (ptrdiff_t)key * DH;
            #pragma unroll
            for (int kc = 0; kc < 4; ++kc) {
                U16x8 u16v; u16v.u = *(const uint4*)(krow + kc*32 + g*8);
                acc[u] = __builtin_amdgcn_mfma_f32_16x16x32_bf16(aq[kc], u16v.s, acc[u], 0, 0, 0);
            }
        }
    }

    // ---- V transpose + LDS writes (loads have had time to land) ----
    vt_xpose_write(VT, vr0, kgp0, dgp0);
    if (two) vt_xpose_write(VT, vr1, kgp1, dgp1);

    // ---- mask + per-wave row max (C layout: col=i=key, row=g*4+r=query) ----
    float sc[3][4], m4[4];
    #pragma unroll
    for (int r = 0; r < 4; ++r) m4[r] = -3e30f;
    #pragma unroll
    for (int u = 0; u < 3; ++u) {
        if (u < nkt) {
            int kt = wave + 4*u;
            int key = k0 + kt*16 + i;
            #pragma unroll
            for (int r = 0; r < 4; ++r) {
                int qrow = s0 + g*4 + r;
                bool valid = (key >= 0) && (key < S_LEN) &&
                             (key >= qrow - half) && (key <= qrow + half);
                float sv = valid ? acc[u][r] * scale : -1e30f;
                sc[u][r] = sv;
                m4[r] = fmaxf(m4[r], sv);
            }
        }
    }
    #pragma unroll
    for (int r = 0; r < 4; ++r) {
        #pragma unroll
        for (int m = 1; m < 16; m <<= 1)
            m4[r] = fmaxf(m4[r], __shfl_xor(m4[r], m, 64));
    }
    if (i == 0) {
        #pragma unroll
        for (int r = 0; r < 4; ++r) pmax[wave][g*4 + r] = m4[r];
    }
    __syncthreads();   // barrier 1: pmax + VT visible

    // ---- softmax: combine max, exp, write P (bf16), partial sums ----
    float M[4], l4[4];
    #pragma unroll
    for (int r = 0; r < 4; ++r) {
        int qr = g*4 + r;
        M[r] = fmaxf(fmaxf(pmax[0][qr], pmax[1][qr]), fmaxf(pmax[2][qr], pmax[3][qr]));
        l4[r] = 0.f;
    }
    #pragma unroll
    for (int u = 0; u < 3; ++u) {
        if (u < nkt) {
            int kt = wave + 4*u;
            #pragma unroll
            for (int r = 0; r < 4; ++r) {
                float p = __expf(sc[u][r] - M[r]);
                l4[r] += p;
                __hip_bfloat16 pb = __float2bfloat16(p);
                Pm[(g*4 + r) * PST + kt*16 + i] = *(unsigned short*)&pb;
            }
        }
    }
    #pragma unroll
    for (int r = 0; r < 4; ++r) {
        #pragma unroll
        for (int m = 1; m < 16; m <<= 1)
            l4[r] += __shfl_xor(l4[r], m, 64);
    }
    if (i == 0) {
        #pragma unroll
        for (int r = 0; r < 4; ++r) psum[wave][g*4 + r] = l4[r];
    }
    __syncthreads();   // barrier 2: P + psum visible

    // ---- Phase B: O = P V for this wave's 32-dim strip ----
    float linv[4];
    #pragma unroll
    for (int r = 0; r < 4; ++r) {
        int qr = g*4 + r;
        linv[r] = 1.0f / (psum[0][qr] + psum[1][qr] + psum[2][qr] + psum[3][qr]);
    }

    short8 ap[5];
    #pragma unroll
    for (int kc = 0; kc < 5; ++kc)
        ap[kc] = *(const short8*)&Pm[i * PST + kc*32 + g*8];

    const int n0 = wave * 32;
    f32x4 oacc[2];
    #pragma unroll
    for (int nt = 0; nt < 2; ++nt) { oacc[nt][0]=0.f; oacc[nt][1]=0.f; oacc[nt][2]=0.f; oacc[nt][3]=0.f; }
    #pragma unroll
    for (int nt = 0; nt < 2; ++nt) {
        int row0 = n0 + nt*16 + i;                 // V^T row = dim
        int dgr = (row0 >> 3) & 7;
        #pragma unroll
        for (int kc = 0; kc < 5; ++kc) {
            int lg = 4*kc + g;
            int sw = lg + dgr; if (sw >= 21) sw -= 21;
            short8 bv = *(const short8*)&VT[row0 * VTS + sw*8];
            oacc[nt] = __builtin_amdgcn_mfma_f32_16x16x32_bf16(ap[kc], bv, oacc[nt], 0, 0, 0);
        }
    }

    // ---- epilogue ----
    #pragma unroll
    for (int nt = 0; nt < 2; ++nt) {
        #pragma unroll
        for (int r = 0; r < 4; ++r) {
            int qrow = s0 + g*4 + r;
            out[((size_t)(b * S_LEN) + qrow) * DH + n0 + nt*16 + i] = oacc[nt][r] * linv[r];
        }
    }
}

extern "C" void kernel_launch(void* const* d_in, const int* in_sizes, int n_in,
                              void* d_out, int out_size, void* d_ws, size_t ws_size,
                              hipStream_t stream) {
    const float* x  = (const float*)d_in[0];
    const float* Wq = (const float*)d_in[1];
    const float* bq = (const float*)d_in[2];
    const float* Wk = (const float*)d_in[3];
    const float* bk = (const float*)d_in[4];
    const float* Wv = (const float*)d_in[5];
    const float* bv = (const float*)d_in[6];
    const int* wsz  = (const int*)d_in[7];

    const int B = 2, S = 4096;
    const int N = B * S;                       // 8192 rows

    __hip_bfloat16* q = (__hip_bfloat16*)d_ws;
    __hip_bfloat16* k = q + (size_t)N * DH;
    __hip_bfloat16* v = k + (size_t)N * DH;
    unsigned short* XH = (unsigned short*)(v + (size_t)N * DH);
    unsigned short* XL = XH + (size_t)N * DH;
    unsigned short* WT = XL + (size_t)N * DH;

    prep_kernel<<<515, 256, 0, stream>>>(x, Wq, Wk, Wv, XH, XL, WT);
    qkv_kernel<<<dim3(256, 3), 256, 0, stream>>>(XH, XL, WT, bq, bk, bv, q, k, v);
    attn_kernel<<<N / TQ, 256, 0, stream>>>(q, k, v, (float*)d_out, wsz);
}

// Round 2
// 84.962 us; speedup vs baseline: 1.1396x; 1.1396x over previous
//
#include <hip/hip_runtime.h>
#include <hip/hip_bf16.h>

typedef __attribute__((ext_vector_type(8))) short short8;
typedef __attribute__((ext_vector_type(4))) float f32x4;

union U16x8 { uint4 u; short8 s; unsigned short us[8]; };

#define S_LEN 4096
#define DH    128
#define TQ    16          // queries per attn block
#define VTS   168         // V^T LDS row stride in u16 (21 groups of 8, 336B rows)
#define PST   168         // P LDS row stride in u16
#define XSTR  136         // x-tile LDS stride (bf16 elems)

// ---------------- Kernel 1: QKV projection via MFMA ------------------------
// x split hi/lo bf16 in LDS (2-term MFMA -> fp32-quality x), W gathered
// straight from global fp32 (64 KB/mat, L2-resident after first touch).
// Grid = (256 row-groups) x (3 mats) = 768 blocks = 3 blocks/CU -> 3 waves/SIMD
// of latency hiding (round-0 structure had 1). No inter-kernel round-trip.
__global__ __launch_bounds__(256) void qkv_kernel(
    const float* __restrict__ x,
    const float* __restrict__ Wq, const float* __restrict__ bq,
    const float* __restrict__ Wk, const float* __restrict__ bk,
    const float* __restrict__ Wv, const float* __restrict__ bv,
    __hip_bfloat16* __restrict__ q, __hip_bfloat16* __restrict__ k,
    __hip_bfloat16* __restrict__ v)
{
    __shared__ __align__(16) unsigned short XH[32 * XSTR];
    __shared__ __align__(16) unsigned short XL[32 * XSTR];

    const int t = threadIdx.x;
    const int row0 = blockIdx.x * 32;
    const int mat = blockIdx.y;

    // ---- stage x as hi/lo bf16 (32 rows; same rows for all 3 mats -> L2) ----
    #pragma unroll
    for (int p = 0; p < 4; ++p) {
        int c = t + p * 256;                 // 0..1023
        int r = c >> 5, cg = c & 31;         // row, float4 group
        float4 xv = *(const float4*)(x + (size_t)(row0 + r) * DH + cg * 4);
        unsigned h[2], l[2];
        #pragma unroll
        for (int hw = 0; hw < 2; ++hw) {
            unsigned hh[2], ll[2];
            #pragma unroll
            for (int j = 0; j < 2; ++j) {
                float xs = (&xv.x)[hw * 2 + j];
                __hip_bfloat16 hb = __float2bfloat16(xs);
                float hf = __bfloat162float(hb);
                __hip_bfloat16 lb = __float2bfloat16(xs - hf);
                hh[j] = *(unsigned short*)&hb;
                ll[j] = *(unsigned short*)&lb;
            }
            h[hw] = hh[0] | (hh[1] << 16);
            l[hw] = ll[0] | (ll[1] << 16);
        }
        *(uint2*)&XH[r * XSTR + cg * 4] = make_uint2(h[0], h[1]);
        *(uint2*)&XL[r * XSTR + cg * 4] = make_uint2(l[0], l[1]);
    }
    __syncthreads();

    const int wave = t >> 6, lane = t & 63;
    const int i = lane & 15, g = lane >> 4;

    // ---- A fragments (row m = i, k = kc*32 + g*8 + j) ----
    short8 ah[2][4], al[2][4];
    #pragma unroll
    for (int rt = 0; rt < 2; ++rt)
        #pragma unroll
        for (int kc = 0; kc < 4; ++kc) {
            ah[rt][kc] = *(const short8*)&XH[(rt*16 + i) * XSTR + kc*32 + g*8];
            al[rt][kc] = *(const short8*)&XL[(rt*16 + i) * XSTR + kc*32 + g*8];
        }

    const float* W = (mat == 0) ? Wq : (mat == 1) ? Wk : Wv;
    const float* bias_p = (mat == 0) ? bq : (mat == 1) ? bk : bv;
    __hip_bfloat16* O = (mat == 0) ? q : (mat == 1) ? k : v;

    #pragma unroll
    for (int ct = 0; ct < 2; ++ct) {
        const int col = wave*32 + ct*16 + i;
        const float bias = bias_p[col];

        // B frags: col n = i, k = kc*32 + g*8 + j (strided gather, L2-hot W)
        short8 bf[4];
        #pragma unroll
        for (int kc = 0; kc < 4; ++kc) {
            const float* wp = W + (size_t)(kc*32 + g*8) * DH + col;
            U16x8 u;
            #pragma unroll
            for (int j = 0; j < 8; ++j) {
                __hip_bfloat16 wb = __float2bfloat16(wp[(size_t)j * DH]);
                u.us[j] = *(unsigned short*)&wb;
            }
            bf[kc] = u.s;
        }

        #pragma unroll
        for (int rt = 0; rt < 2; ++rt) {
            f32x4 acc; acc[0]=0.f; acc[1]=0.f; acc[2]=0.f; acc[3]=0.f;
            #pragma unroll
            for (int kc = 0; kc < 4; ++kc) {
                acc = __builtin_amdgcn_mfma_f32_16x16x32_bf16(ah[rt][kc], bf[kc], acc, 0, 0, 0);
                acc = __builtin_amdgcn_mfma_f32_16x16x32_bf16(al[rt][kc], bf[kc], acc, 0, 0, 0);
            }
            #pragma unroll
            for (int r = 0; r < 4; ++r) {
                O[(size_t)(row0 + rt*16 + g*4 + r) * DH + col] =
                    __float2bfloat16(acc[r] + bias);
            }
        }
    }
}

// ---- 8x8 u16 in-register transpose (32 v_perm) + swizzled VT write --------
__device__ inline void vt_xpose_write(unsigned short* VT, const uint4* vr,
                                      int kgp, int dgp)
{
    unsigned w[8][4];   // w[dim][key-pair]
    #pragma unroll
    for (int p = 0; p < 4; ++p) {
        #pragma unroll
        for (int j = 0; j < 4; ++j) {
            unsigned xlo = ((const unsigned*)&vr[2*p])[j];     // key 2p,  dims 2j,2j+1
            unsigned ylo = ((const unsigned*)&vr[2*p+1])[j];   // key 2p+1
            w[2*j][p]   = __builtin_amdgcn_perm(ylo, xlo, 0x05040100u);
            w[2*j+1][p] = __builtin_amdgcn_perm(ylo, xlo, 0x07060302u);
        }
    }
    int sw = kgp + (dgp & 7); if (sw >= 21) sw -= 21;   // bank swizzle, rotate mod 21
    #pragma unroll
    for (int d = 0; d < 8; ++d) {
        int row = dgp*8 + d;
        *(uint4*)&VT[row*VTS + sw*8] =
            make_uint4(w[d][0], w[d][1], w[d][2], w[d][3]);
    }
}

// ---------------- Kernel 2: MFMA sliding-window attention -------------------
// Block = 4 waves, 16 queries, 160-key staged window. Phase A: waves own key
// tiles {w, w+4, w+8}, B-frags gathered straight from global K (cached).
// V transposed into LDS via register 8x8 transpose. Phase B: waves own
// 32-dim strips, P & V^T frags are ds_read_b128.
// Block index is XCD-swizzled (512 % 8 == 0 -> bijective) so each XCD's
// resident q-tiles are contiguous -> K/V window stays L2-resident.
__global__ __launch_bounds__(256) void attn_kernel(
    const __hip_bfloat16* __restrict__ qg,
    const __hip_bfloat16* __restrict__ kg,
    const __hip_bfloat16* __restrict__ vg,
    float* __restrict__ out, const int* __restrict__ wsz)
{
    __shared__ __align__(16) unsigned short VT[128 * VTS];   // 43 KB
    __shared__ __align__(16) unsigned short Pm[TQ * PST];    // 5.25 KB
    __shared__ float pmax[4][16];
    __shared__ float psum[4][16];

    const int t    = threadIdx.x;
    const int wave = t >> 6, lane = t & 63;
    const int i = lane & 15, g = lane >> 4;
    const int bid  = blockIdx.x;
    const int qblk = (bid & 7) * 64 + (bid >> 3);   // XCD swizzle, 512 blocks
    const int b    = qblk >> 8;
    const int s0   = (qblk & 255) * TQ;
    const int k0   = s0 - 64;
    const int half = wsz[0] >> 1;
    const float scale = 0.08838834764831845f;

    const __hip_bfloat16* kb = kg + (size_t)b * S_LEN * DH;
    const __hip_bfloat16* vb = vg + (size_t)b * S_LEN * DH;

    // ---- V tile loads (issued first; 8 keys x 8 dims per tile) ----
    const int kgp0 = t >> 4, dgp0 = t & 15;          // tile t
    const bool two = (t & 3) == 0;
    const int tau2 = 256 + (t >> 2);                 // tiles 256..319
    const int kgp1 = tau2 >> 4, dgp1 = tau2 & 15;
    uint4 vr0[8], vr1[8];
    #pragma unroll
    for (int r = 0; r < 8; ++r) {
        int key = k0 + kgp0*8 + r;
        uint4 val = make_uint4(0u,0u,0u,0u);
        if (key >= 0 && key < S_LEN)
            val = *(const uint4*)(vb + (size_t)key * DH + dgp0*8);
        vr0[r] = val;
    }
    #pragma unroll
    for (int r = 0; r < 8; ++r) {
        int key = k0 + kgp1*8 + r;
        uint4 val = make_uint4(0u,0u,0u,0u);
        if (two && key >= 0 && key < S_LEN)
            val = *(const uint4*)(vb + (size_t)key * DH + dgp1*8);
        vr1[r] = val;
    }

    // ---- Q A-frags from global (same rows for all 4 waves -> L1 broadcast) ----
    short8 aq[4];
    {
        const __hip_bfloat16* qrow = qg + (size_t)(b * S_LEN + s0 + i) * DH;
        #pragma unroll
        for (int kc = 0; kc < 4; ++kc) {
            U16x8 u; u.u = *(const uint4*)(qrow + kc*32 + g*8);
            aq[kc] = u.s;
        }
    }

    // ---- Phase A: scores for owned key tiles, B-frags straight from global ----
    const int nkt = (wave < 2) ? 3 : 2;
    f32x4 acc[3];
    #pragma unroll
    for (int u = 0; u < 3; ++u) { acc[u][0]=0.f; acc[u][1]=0.f; acc[u][2]=0.f; acc[u][3]=0.f; }
    #pragma unroll
    for (int u = 0; u < 3; ++u) {
        if (u < nkt) {
            int kt = wave + 4*u;
            int key = k0 + kt*16 + i;               // may be OOB: garbage -> masked
            const __hip_bfloat16* krow = kb + (ptrdiff_t)key * DH;
            #pragma unroll
            for (int kc = 0; kc < 4; ++kc) {
                U16x8 u16v; u16v.u = *(const uint4*)(krow + kc*32 + g*8);
                acc[u] = __builtin_amdgcn_mfma_f32_16x16x32_bf16(aq[kc], u16v.s, acc[u], 0, 0, 0);
            }
        }
    }

    // ---- V transpose + LDS writes (loads have had time to land) ----
    vt_xpose_write(VT, vr0, kgp0, dgp0);
    if (two) vt_xpose_write(VT, vr1, kgp1, dgp1);

    // ---- mask + per-wave row max (C layout: col=i=key, row=g*4+r=query) ----
    float sc[3][4], m4[4];
    #pragma unroll
    for (int r = 0; r < 4; ++r) m4[r] = -3e30f;
    #pragma unroll
    for (int u = 0; u < 3; ++u) {
        if (u < nkt) {
            int kt = wave + 4*u;
            int key = k0 + kt*16 + i;
            #pragma unroll
            for (int r = 0; r < 4; ++r) {
                int qrow = s0 + g*4 + r;
                bool valid = (key >= 0) && (key < S_LEN) &&
                             (key >= qrow - half) && (key <= qrow + half);
                float sv = valid ? acc[u][r] * scale : -1e30f;
                sc[u][r] = sv;
                m4[r] = fmaxf(m4[r], sv);
            }
        }
    }
    #pragma unroll
    for (int r = 0; r < 4; ++r) {
        #pragma unroll
        for (int m = 1; m < 16; m <<= 1)
            m4[r] = fmaxf(m4[r], __shfl_xor(m4[r], m, 64));
    }
    if (i == 0) {
        #pragma unroll
        for (int r = 0; r < 4; ++r) pmax[wave][g*4 + r] = m4[r];
    }
    __syncthreads();   // barrier 1: pmax + VT visible

    // ---- softmax: combine max, exp, write P (bf16), partial sums ----
    float M[4], l4[4];
    #pragma unroll
    for (int r = 0; r < 4; ++r) {
        int qr = g*4 + r;
        M[r] = fmaxf(fmaxf(pmax[0][qr], pmax[1][qr]), fmaxf(pmax[2][qr], pmax[3][qr]));
        l4[r] = 0.f;
    }
    #pragma unroll
    for (int u = 0; u < 3; ++u) {
        if (u < nkt) {
            int kt = wave + 4*u;
            #pragma unroll
            for (int r = 0; r < 4; ++r) {
                float p = __expf(sc[u][r] - M[r]);
                l4[r] += p;
                __hip_bfloat16 pb = __float2bfloat16(p);
                Pm[(g*4 + r) * PST + kt*16 + i] = *(unsigned short*)&pb;
            }
        }
    }
    #pragma unroll
    for (int r = 0; r < 4; ++r) {
        #pragma unroll
        for (int m = 1; m < 16; m <<= 1)
            l4[r] += __shfl_xor(l4[r], m, 64);
    }
    if (i == 0) {
        #pragma unroll
        for (int r = 0; r < 4; ++r) psum[wave][g*4 + r] = l4[r];
    }
    __syncthreads();   // barrier 2: P + psum visible

    // ---- Phase B: O = P V for this wave's 32-dim strip ----
    float linv[4];
    #pragma unroll
    for (int r = 0; r < 4; ++r) {
        int qr = g*4 + r;
        linv[r] = 1.0f / (psum[0][qr] + psum[1][qr] + psum[2][qr] + psum[3][qr]);
    }

    short8 ap[5];
    #pragma unroll
    for (int kc = 0; kc < 5; ++kc)
        ap[kc] = *(const short8*)&Pm[i * PST + kc*32 + g*8];

    const int n0 = wave * 32;
    f32x4 oacc[2];
    #pragma unroll
    for (int nt = 0; nt < 2; ++nt) { oacc[nt][0]=0.f; oacc[nt][1]=0.f; oacc[nt][2]=0.f; oacc[nt][3]=0.f; }
    #pragma unroll
    for (int nt = 0; nt < 2; ++nt) {
        int row0 = n0 + nt*16 + i;                 // V^T row = dim
        int dgr = (row0 >> 3) & 7;
        #pragma unroll
        for (int kc = 0; kc < 5; ++kc) {
            int lg = 4*kc + g;
            int sw = lg + dgr; if (sw >= 21) sw -= 21;
            short8 bv = *(const short8*)&VT[row0 * VTS + sw*8];
            oacc[nt] = __builtin_amdgcn_mfma_f32_16x16x32_bf16(ap[kc], bv, oacc[nt], 0, 0, 0);
        }
    }

    // ---- epilogue ----
    #pragma unroll
    for (int nt = 0; nt < 2; ++nt) {
        #pragma unroll
        for (int r = 0; r < 4; ++r) {
            int qrow = s0 + g*4 + r;
            out[((size_t)(b * S_LEN) + qrow) * DH + n0 + nt*16 + i] = oacc[nt][r] * linv[r];
        }
    }
}

extern "C" void kernel_launch(void* const* d_in, const int* in_sizes, int n_in,
                              void* d_out, int out_size, void* d_ws, size_t ws_size,
                              hipStream_t stream) {
    const float* x  = (const float*)d_in[0];
    const float* Wq = (const float*)d_in[1];
    const float* bq = (const float*)d_in[2];
    const float* Wk = (const float*)d_in[3];
    const float* bk = (const float*)d_in[4];
    const float* Wv = (const float*)d_in[5];
    const float* bv = (const float*)d_in[6];
    const int* wsz  = (const int*)d_in[7];

    const int B = 2, S = 4096;
    const int N = B * S;                       // 8192 rows

    __hip_bfloat16* q = (__hip_bfloat16*)d_ws;
    __hip_bfloat16* k = q + (size_t)N * DH;
    __hip_bfloat16* v = k + (size_t)N * DH;

    qkv_kernel<<<dim3(256, 3), 256, 0, stream>>>(x, Wq, bq, Wk, bk, Wv, bv, q, k, v);
    attn_kernel<<<N / TQ, 256, 0, stream>>>(q, k, v, (float*)d_out, wsz);
}